// Round 10
// baseline (1561.723 us; speedup 1.0000x reference)
//
#include <hip/hip_runtime.h>
#include <hip/hip_bf16.h>
#include <stdint.h>

#define NE 8
#define HID 512
#define OBS 32
#define ACT 16
#define DIN 48
#define DINP 64     // padded input dim
#define BTOT 32768
#define TM 128      // rows per block
#define NH 80       // padded head outputs (66 -> 80)

typedef short bf16x8 __attribute__((ext_vector_type(8)));
typedef float f32x4 __attribute__((ext_vector_type(4)));

__device__ __forceinline__ unsigned short f2bf(float f) {
    union { float f; unsigned u; } v; v.f = f;
    unsigned u = v.u + 0x7FFF + ((v.u >> 16) & 1);
    return (unsigned short)(u >> 16);
}

// ---------------- prep kernels ----------------

// X[b][c] = normalized concat(states, actions), zero-padded to 64, bf16
__global__ void prep_x(const float* __restrict__ st, const float* __restrict__ ac,
                       const float* __restrict__ sm, const float* __restrict__ ss,
                       const float* __restrict__ am, const float* __restrict__ as_,
                       unsigned short* __restrict__ X) {
    int idx = blockIdx.x * 256 + threadIdx.x;   // B*64 total
    int b = idx >> 6, c = idx & 63;
    float v = 0.f;
    if (c < OBS) v = (st[b * OBS + c] - sm[c]) / ss[c];
    else if (c < DIN) { int ca = c - OBS; v = (ac[b * ACT + ca] - am[ca]) / as_[ca]; }
    X[idx] = f2bf(v);
}

// T1[e][n][k] = W1[e][k][n] (k<48 else 0), bf16, K padded to 64
__global__ void prep_w1(const float* __restrict__ W1, unsigned short* __restrict__ T1) {
    int idx = blockIdx.x * 256 + threadIdx.x;   // 8*512*64
    int k = idx & 63, n = (idx >> 6) & 511, e = idx >> 15;
    float v = (k < DIN) ? W1[((size_t)e * DIN + k) * HID + n] : 0.f;
    T1[idx] = f2bf(v);
}

// Transposed bf16 copies of W2/W3/W4: T[z][n][k] = Wsrc[e][k][n], z = l*8+e
__global__ void prep_wh(const float* __restrict__ W2, const float* __restrict__ W3,
                        const float* __restrict__ W4, unsigned short* __restrict__ T) {
    __shared__ float tile[32][33];
    int z = blockIdx.z;
    const float* src = (z < 8 ? W2 : (z < 16 ? W3 : W4)) + (size_t)(z & 7) * HID * HID;
    unsigned short* dst = T + (size_t)z * HID * HID;
    int n0 = blockIdx.x * 32, k0 = blockIdx.y * 32;
    int tx = threadIdx.x, ty = threadIdx.y;     // 32 x 8
    #pragma unroll
    for (int i = 0; i < 32; i += 8)
        tile[ty + i][tx] = src[(size_t)(k0 + ty + i) * HID + n0 + tx];
    __syncthreads();
    #pragma unroll
    for (int i = 0; i < 32; i += 8)
        dst[(size_t)(n0 + ty + i) * HID + k0 + tx] = f2bf(tile[tx][ty + i]);
}

// Fused head weights TH[e][n][k] (n<32 means, <64 logstd, 64 reward, 65 done, rest 0)
// and fused head bias BH[e][n]
__global__ void prep_head(const float* __restrict__ Wm, const float* __restrict__ Wls,
                          const float* __restrict__ Wr, const float* __restrict__ Wd,
                          const float* __restrict__ bm, const float* __restrict__ bls,
                          const float* __restrict__ br, const float* __restrict__ bd,
                          unsigned short* __restrict__ TH, float* __restrict__ BH) {
    int idx = blockIdx.x * 256 + threadIdx.x;   // 8*80*512
    if (idx < NE * NH * HID) {
        int k = idx & 511, n = (idx >> 9) % NH, e = idx / (NH * HID);
        float v = 0.f;
        if (n < 32)       v = Wm [((size_t)e * HID + k) * OBS + n];
        else if (n < 64)  v = Wls[((size_t)e * HID + k) * OBS + (n - 32)];
        else if (n == 64) v = Wr [(size_t)e * HID + k];
        else if (n == 65) v = Wd [(size_t)e * HID + k];
        TH[idx] = f2bf(v);
    }
    if (idx < NE * NH) {
        int n = idx % NH, e = idx / NH;
        float v = 0.f;
        if (n < 32)       v = bm [e * OBS + n];
        else if (n < 64)  v = bls[e * OBS + (n - 32)];
        else if (n == 64) v = br [e];
        else if (n == 65) v = bd [e];
        BH[idx] = v;
    }
}

// ---------------- main fused kernel ----------------

__device__ __forceinline__ bf16x8 load_a(const unsigned short* hb, int row, int k) {
    int off = row * 1024 + ((k * 2) ^ ((row & 7) << 4));
    return *(const bf16x8*)((const char*)hb + off);
}

// 8 waves; each wave owns ALL 128 rows x 64 cols (cols = wid*64 .. +63).
// Per ks-step: 4 B-frag global loads + 8 A-frag LDS reads feed 32 MFMAs
// (2x the arithmetic intensity of the TM=64 version). B depth-1 register
// double buffer; round-4-proven barrier structure.
template<int KD, bool RELU>
__device__ __forceinline__ void mlp_layer(const unsigned short* __restrict__ Tw,
                                          const float* __restrict__ bias,
                                          unsigned short* __restrict__ hb,
                                          int lane, int wid) {
    const int l15 = lane & 15, lk = (lane >> 4) * 8;
    const int col0 = wid * 64;
    constexpr int NK = KD / 32;

    f32x4 acc[8][4];
    #pragma unroll
    for (int ct = 0; ct < 4; ++ct) {
        float bv = bias[col0 + ct * 16 + l15];
        f32x4 b4 = {bv, bv, bv, bv};
        #pragma unroll
        for (int rt = 0; rt < 8; ++rt) acc[rt][ct] = b4;
    }

    // B row base for this lane: row (col0 + ct*16 + l15), k = ks*32 + lk
    const unsigned short* Bb = Tw + (size_t)(col0 + l15) * KD + lk;

    bf16x8 bcur[4], bnxt[4];
    #pragma unroll
    for (int ct = 0; ct < 4; ++ct)
        bcur[ct] = *(const bf16x8*)(Bb + ct * 16 * KD);

    #pragma unroll
    for (int ks = 0; ks < NK; ++ks) {
        const int k = ks * 32 + lk;
        if (ks + 1 < NK) {
            #pragma unroll
            for (int ct = 0; ct < 4; ++ct)
                bnxt[ct] = *(const bf16x8*)(Bb + ct * 16 * KD + (ks + 1) * 32);
        }
        #pragma unroll
        for (int rtp = 0; rtp < 4; ++rtp) {
            bf16x8 a0 = load_a(hb, (2 * rtp)     * 16 + l15, k);
            bf16x8 a1 = load_a(hb, (2 * rtp + 1) * 16 + l15, k);
            #pragma unroll
            for (int ct = 0; ct < 4; ++ct) {
                acc[2 * rtp][ct]     = __builtin_amdgcn_mfma_f32_16x16x32_bf16(a0, bcur[ct], acc[2 * rtp][ct],     0, 0, 0);
                acc[2 * rtp + 1][ct] = __builtin_amdgcn_mfma_f32_16x16x32_bf16(a1, bcur[ct], acc[2 * rtp + 1][ct], 0, 0, 0);
            }
        }
        if (ks + 1 < NK) {
            #pragma unroll
            for (int ct = 0; ct < 4; ++ct) bcur[ct] = bnxt[ct];
        }
    }
    __syncthreads();
    #pragma unroll
    for (int rt = 0; rt < 8; ++rt)
        #pragma unroll
        for (int ct = 0; ct < 4; ++ct)
            #pragma unroll
            for (int j = 0; j < 4; ++j) {
                int row = rt * 16 + (lane >> 4) * 4 + j;
                int col = col0 + ct * 16 + l15;
                float v = acc[rt][ct][j];
                if (RELU) v = fmaxf(v, 0.f);
                *(unsigned short*)((char*)hb + row * 1024 + ((col * 2) ^ ((row & 7) << 4))) = f2bf(v);
            }
    __syncthreads();
}

__launch_bounds__(512, 2)
__global__ void ens_mlp(const unsigned short* __restrict__ X,
                        const unsigned short* __restrict__ T1, const unsigned short* __restrict__ T2,
                        const unsigned short* __restrict__ T3, const unsigned short* __restrict__ T4,
                        const unsigned short* __restrict__ TH,
                        const float* __restrict__ b1, const float* __restrict__ b2,
                        const float* __restrict__ b3, const float* __restrict__ b4,
                        const float* __restrict__ BH,
                        const float* __restrict__ dmean, const float* __restrict__ dstd,
                        float* __restrict__ out) {
    __shared__ unsigned short hbuf[TM * HID];   // 128 KB, XOR-swizzled rows
    const int bid = blockIdx.x;
    const int e = bid & 7;                      // ensemble -> XCD affinity
    const int tile = bid >> 3;
    const int row0 = tile * TM;
    const int tid = threadIdx.x, lane = tid & 63, wid = tid >> 6;

    // stage X tile (128 rows x 64 bf16), swizzled; 1024 chunks / 512 threads
    #pragma unroll
    for (int i = 0; i < 2; ++i) {
        int idx = tid + 512 * i;
        int r = idx >> 3, c = idx & 7;          // 16B chunk index
        int4 v = *(const int4*)(X + (size_t)(row0 + r) * DINP + c * 8);
        *(int4*)((char*)hbuf + r * 1024 + ((c ^ (r & 7)) << 4)) = v;
    }
    __syncthreads();

    mlp_layer<64,  true>(T1 + (size_t)e * HID * 64,  b1 + e * HID, hbuf, lane, wid);
    mlp_layer<512, true>(T2 + (size_t)e * HID * HID, b2 + e * HID, hbuf, lane, wid);
    mlp_layer<512, true>(T3 + (size_t)e * HID * HID, b3 + e * HID, hbuf, lane, wid);
    mlp_layer<512, true>(T4 + (size_t)e * HID * HID, b4 + e * HID, hbuf, lane, wid);

    // ---- heads: 40 tile-jobs (rt 0..7, ct 0..4) over 8 waves = 5 each ----
    const int l15 = lane & 15, lk = (lane >> 4) * 8;
    const unsigned short* THe = TH + (size_t)e * NH * HID;
    const float* BHe = BH + e * NH;

    int rtj[5], ctj[5];
    f32x4 h[5];
    #pragma unroll
    for (int i = 0; i < 5; ++i) {
        int j = wid + 8 * i;                    // 0..39, exactly covers 40 jobs
        rtj[i] = j / 5; ctj[i] = j % 5;
        float bv = BHe[ctj[i] * 16 + l15];
        h[i] = (f32x4){bv, bv, bv, bv};
    }

    #pragma unroll
    for (int ks = 0; ks < 16; ++ks) {
        int k = ks * 32 + lk;
        #pragma unroll
        for (int i = 0; i < 5; ++i) {
            bf16x8 a = load_a(hbuf, rtj[i] * 16 + l15, k);
            bf16x8 w = *(const bf16x8*)(THe + (size_t)(ctj[i] * 16 + l15) * HID + k);
            h[i] = __builtin_amdgcn_mfma_f32_16x16x32_bf16(a, w, h[i], 0, 0, 0);
        }
    }

    // ---- epilogue: clip/exp/denorm, write concatenated fp32 outputs ----
    const size_t STDS_OFF = (size_t)NE * BTOT * OBS;
    const size_t REW_OFF  = 2 * STDS_OFF;
    const size_t DONE_OFF = REW_OFF + (size_t)NE * BTOT;

    #pragma unroll
    for (int i = 0; i < 5; ++i) {
        int col = ctj[i] * 16 + l15;
        #pragma unroll
        for (int j = 0; j < 4; ++j) {
            int row = row0 + rtj[i] * 16 + (lane >> 4) * 4 + j;
            size_t rb = (size_t)e * BTOT + row;
            float x = h[i][j];
            if (col < 32) {
                out[rb * 32 + col] = x * dstd[col] + dmean[col];
            } else if (col < 64) {
                int c = col - 32;
                float ls = fminf(fmaxf(x, -10.f), 0.5f);
                out[STDS_OFF + rb * 32 + c] = expf(ls) * dstd[c];
            } else if (col == 64) {
                out[REW_OFF + rb] = x;
            } else if (col == 65) {
                out[DONE_OFF + rb] = x;
            }
        }
    }
}

// ---------------- launch ----------------

extern "C" void kernel_launch(void* const* d_in, const int* in_sizes, int n_in,
                              void* d_out, int out_size, void* d_ws, size_t ws_size,
                              hipStream_t stream) {
    const float* states  = (const float*)d_in[0];
    const float* actions = (const float*)d_in[1];
    const float* smean   = (const float*)d_in[2];
    const float* sstd    = (const float*)d_in[3];
    const float* amean   = (const float*)d_in[4];
    const float* astd    = (const float*)d_in[5];
    const float* dmean   = (const float*)d_in[6];
    const float* dstd    = (const float*)d_in[7];
    const float* W1 = (const float*)d_in[8];
    const float* b1 = (const float*)d_in[9];
    const float* W2 = (const float*)d_in[10];
    const float* b2 = (const float*)d_in[11];
    const float* W3 = (const float*)d_in[12];
    const float* b3 = (const float*)d_in[13];
    const float* W4 = (const float*)d_in[14];
    const float* b4 = (const float*)d_in[15];
    const float* Wm = (const float*)d_in[16];
    const float* bm = (const float*)d_in[17];
    const float* Wls = (const float*)d_in[18];
    const float* bls = (const float*)d_in[19];
    const float* Wr = (const float*)d_in[20];
    const float* br = (const float*)d_in[21];
    const float* Wd = (const float*)d_in[22];
    const float* bd = (const float*)d_in[23];

    char* ws = (char*)d_ws;
    unsigned short* X  = (unsigned short*)(ws);                 // 4,194,304 B
    unsigned short* T1 = (unsigned short*)(ws + 4194304);       //   524,288 B
    unsigned short* T2 = (unsigned short*)(ws + 4718592);       // 4,194,304 B
    unsigned short* T3 = (unsigned short*)(ws + 8912896);
    unsigned short* T4 = (unsigned short*)(ws + 13107200);
    unsigned short* TH = (unsigned short*)(ws + 17301504);      //   655,360 B
    float*          BH = (float*)(ws + 17956864);               //     2,560 B

    prep_x<<<(BTOT * 64) / 256, 256, 0, stream>>>(states, actions, smean, sstd, amean, astd, X);
    prep_w1<<<(NE * HID * 64) / 256, 256, 0, stream>>>(W1, T1);
    dim3 gT(16, 16, 24), bT(32, 8);
    prep_wh<<<gT, bT, 0, stream>>>(W2, W3, W4, T2);
    prep_head<<<(NE * NH * HID) / 256, 256, 0, stream>>>(Wm, Wls, Wr, Wd, bm, bls, br, bd, TH, BH);

    ens_mlp<<<NE * (BTOT / TM), 512, 0, stream>>>(X, T1, T2, T3, T4, TH,
                                                  b1, b2, b3, b4, BH, dmean, dstd,
                                                  (float*)d_out);
}

// Round 11
// 670.306 us; speedup vs baseline: 2.3299x; 2.3299x over previous
//
#include <hip/hip_runtime.h>
#include <hip/hip_bf16.h>
#include <stdint.h>

#define NE 8
#define HID 512
#define OBS 32
#define ACT 16
#define DIN 48
#define DINP 64     // padded input dim
#define BTOT 32768
#define TM 64       // rows per block
#define NH 80       // padded head outputs (66 -> 80)

typedef short bf16x8 __attribute__((ext_vector_type(8)));
typedef short bf16x8s __attribute__((ext_vector_type(8)));
typedef float f32x4 __attribute__((ext_vector_type(4)));

__device__ __forceinline__ unsigned short f2bf(float f) {
    union { float f; unsigned u; } v; v.f = f;
    unsigned u = v.u + 0x7FFF + ((v.u >> 16) & 1);
    return (unsigned short)(u >> 16);
}

// ---------------- prep kernels ----------------

// X[b][c] = normalized concat(states, actions), zero-padded to 64, bf16
__global__ void prep_x(const float* __restrict__ st, const float* __restrict__ ac,
                       const float* __restrict__ sm, const float* __restrict__ ss,
                       const float* __restrict__ am, const float* __restrict__ as_,
                       unsigned short* __restrict__ X) {
    int idx = blockIdx.x * 256 + threadIdx.x;   // B*64 total
    int b = idx >> 6, c = idx & 63;
    float v = 0.f;
    if (c < OBS) v = (st[b * OBS + c] - sm[c]) / ss[c];
    else if (c < DIN) { int ca = c - OBS; v = (ac[b * ACT + ca] - am[ca]) / as_[ca]; }
    X[idx] = f2bf(v);
}

// T1c: chunked layer-1 weights. chunk linear = ((e*2+ks)*4+kc)*512 + n,
// chunk = 8 bf16 = W1[e][ks*32+kc*8+j][n], j=0..7 (k<48 real, else 0).
__global__ void prep_w1(const float* __restrict__ W1, unsigned short* __restrict__ T1c) {
    int idx = blockIdx.x * 256 + threadIdx.x;   // 8*2*4*512 = 32768 chunks
    int n = idx & 511, kc = (idx >> 9) & 3, ks = (idx >> 11) & 1, e = idx >> 12;
    bf16x8s c8;
    #pragma unroll
    for (int j = 0; j < 8; ++j) {
        int k = ks * 32 + kc * 8 + j;
        float v = (k < DIN) ? W1[((size_t)e * DIN + k) * HID + n] : 0.f;
        c8[j] = (short)f2bf(v);
    }
    *(bf16x8s*)(T1c + (size_t)idx * 8) = c8;
}

// T2c/T3c/T4c: chunked hidden weights. Per (l,e): chunk ((ks*4)+kc)*512+n =
// W[e][ks*32+kc*8+j][n]. z = l*8+e over 24.
__global__ void prep_wh(const float* __restrict__ W2, const float* __restrict__ W3,
                        const float* __restrict__ W4,
                        unsigned short* __restrict__ T2c, unsigned short* __restrict__ T3c,
                        unsigned short* __restrict__ T4c) {
    int idx = blockIdx.x * 256 + threadIdx.x;   // 24 * 32768 = 786432
    int n = idx & 511, kc = (idx >> 9) & 3, ks = (idx >> 11) & 15, z = idx >> 15;
    int l = z >> 3, e = z & 7;
    const float* src = (l == 0 ? W2 : (l == 1 ? W3 : W4)) + (size_t)e * HID * HID;
    unsigned short* dst = (l == 0 ? T2c : (l == 1 ? T3c : T4c));
    bf16x8s c8;
    #pragma unroll
    for (int j = 0; j < 8; ++j) {
        int k = ks * 32 + kc * 8 + j;
        c8[j] = (short)f2bf(src[(size_t)k * HID + n]);
    }
    size_t chunk = (((size_t)e * 16 + ks) * 4 + kc) * 512 + n;
    *(bf16x8s*)(dst + chunk * 8) = c8;
}

// THc: chunked fused head weights [e][ks16][kc4][n80] + fused bias BH[e][80].
__global__ void prep_head(const float* __restrict__ Wm, const float* __restrict__ Wls,
                          const float* __restrict__ Wr, const float* __restrict__ Wd,
                          const float* __restrict__ bm, const float* __restrict__ bls,
                          const float* __restrict__ br, const float* __restrict__ bd,
                          unsigned short* __restrict__ THc, float* __restrict__ BH) {
    int idx = blockIdx.x * 256 + threadIdx.x;   // 8*16*4*80 = 40960 chunks
    if (idx < NE * 16 * 4 * NH) {
        int n = idx % NH, kc = (idx / NH) & 3, ks = (idx / (NH * 4)) & 15, e = idx / (NH * 64);
        bf16x8s c8;
        #pragma unroll
        for (int j = 0; j < 8; ++j) {
            int k = ks * 32 + kc * 8 + j;
            float v = 0.f;
            if (n < 32)       v = Wm [((size_t)e * HID + k) * OBS + n];
            else if (n < 64)  v = Wls[((size_t)e * HID + k) * OBS + (n - 32)];
            else if (n == 64) v = Wr [(size_t)e * HID + k];
            else if (n == 65) v = Wd [(size_t)e * HID + k];
            c8[j] = (short)f2bf(v);
        }
        *(bf16x8s*)(THc + (size_t)idx * 8) = c8;
    }
    if (idx < NE * NH) {
        int n = idx % NH, e = idx / NH;
        float v = 0.f;
        if (n < 32)       v = bm [e * OBS + n];
        else if (n < 64)  v = bls[e * OBS + (n - 32)];
        else if (n == 64) v = br [e];
        else if (n == 65) v = bd [e];
        BH[idx] = v;
    }
}

// ---------------- main fused kernel ----------------

__device__ __forceinline__ bf16x8 load_a(const unsigned short* hb, int row, int k) {
    int off = row * 1024 + ((k * 2) ^ ((row & 7) << 4));
    return *(const bf16x8*)((const char*)hb + off);
}

// async global->LDS, 16B per lane, linear: lds dest = uniform base + lane*16
__device__ __forceinline__ void gl_lds16(const unsigned short* g, unsigned short* l) {
    __builtin_amdgcn_global_load_lds(
        (const __attribute__((address_space(1))) unsigned int*)g,
        (__attribute__((address_space(3))) unsigned int*)l, 16, 0, 0);
}

// stage one 32KB B-tile (2048 chunks): 8 waves x 4 issues x 1KB
__device__ __forceinline__ void stage32(const unsigned short* __restrict__ src,
                                        unsigned short* dst, int wid, int lane) {
    #pragma unroll
    for (int i = 0; i < 4; ++i) {
        int off = (wid * 4 + i) * 512;          // elems (1KB)
        gl_lds16(src + off + lane * 8, dst + off);
    }
}

// stage one 5KB head tile (320 chunks): waves 0..4, 1KB each
__device__ __forceinline__ void stageH(const unsigned short* __restrict__ src,
                                       unsigned short* dst, int wid, int lane) {
    if (wid < 5) gl_lds16(src + wid * 512 + lane * 8, dst + wid * 512);
}

// One MLP layer, 2-phase LDS double-buffered B. Each wave owns 64 rows x 64
// cols. Per step (BK=32): stage next tile (global_load_lds) -> 4 B ds_reads +
// 4 A ds_reads -> 16 MFMA -> __syncthreads (its vmcnt(0) drains the stage
// issued at step START, hidden under this step's compute).
// NEXTK: 0 = stage next 2048-chunk layer tile, 1 = stage head tile, 2 = none.
template<int NK, int NEXTK>
__device__ __forceinline__ void mlp_layer(const unsigned short* __restrict__ Tc,
                                          const unsigned short* __restrict__ nextTc,
                                          const float* __restrict__ bias,
                                          unsigned short* __restrict__ hb,
                                          unsigned short* __restrict__ bbuf,
                                          int lane, int wid) {
    const int l15 = lane & 15, lk = (lane >> 4) * 8, kc = lane >> 4;
    const int col0 = wid * 64;

    f32x4 acc[4][4];
    #pragma unroll
    for (int ct = 0; ct < 4; ++ct) {
        float bv = bias[col0 + ct * 16 + l15];
        f32x4 b4 = {bv, bv, bv, bv};
        #pragma unroll
        for (int rt = 0; rt < 4; ++rt) acc[rt][ct] = b4;
    }

    #pragma unroll
    for (int ks = 0; ks < NK; ++ks) {
        if (ks + 1 < NK)
            stage32(Tc + (size_t)(ks + 1) * 2048 * 8, bbuf + ((ks + 1) & 1) * 16384, wid, lane);
        const unsigned short* bb = bbuf + (ks & 1) * 16384;

        bf16x8 bfrag[4];
        #pragma unroll
        for (int ct = 0; ct < 4; ++ct)
            bfrag[ct] = *(const bf16x8*)(bb + (size_t)(kc * 512 + col0 + ct * 16 + l15) * 8);

        const int k = ks * 32 + lk;
        bf16x8 a0 = load_a(hb, 0 * 16 + l15, k);
        bf16x8 a1 = load_a(hb, 1 * 16 + l15, k);
        #pragma unroll
        for (int ct = 0; ct < 4; ++ct) {
            acc[0][ct] = __builtin_amdgcn_mfma_f32_16x16x32_bf16(a0, bfrag[ct], acc[0][ct], 0, 0, 0);
            acc[1][ct] = __builtin_amdgcn_mfma_f32_16x16x32_bf16(a1, bfrag[ct], acc[1][ct], 0, 0, 0);
        }
        bf16x8 a2 = load_a(hb, 2 * 16 + l15, k);
        bf16x8 a3 = load_a(hb, 3 * 16 + l15, k);
        #pragma unroll
        for (int ct = 0; ct < 4; ++ct) {
            acc[2][ct] = __builtin_amdgcn_mfma_f32_16x16x32_bf16(a2, bfrag[ct], acc[2][ct], 0, 0, 0);
            acc[3][ct] = __builtin_amdgcn_mfma_f32_16x16x32_bf16(a3, bfrag[ct], acc[3][ct], 0, 0, 0);
        }
        __syncthreads();   // drains this step's stage (issued a full phase ago)
    }

    // epilogue: ReLU + write activations back to hbuf (swizzled)
    #pragma unroll
    for (int rt = 0; rt < 4; ++rt)
        #pragma unroll
        for (int ct = 0; ct < 4; ++ct)
            #pragma unroll
            for (int j = 0; j < 4; ++j) {
                int row = rt * 16 + (lane >> 4) * 4 + j;
                int col = col0 + ct * 16 + l15;
                float v = fmaxf(acc[rt][ct][j], 0.f);
                *(unsigned short*)((char*)hb + row * 1024 + ((col * 2) ^ ((row & 7) << 4))) = f2bf(v);
            }
    // prefetch next phase's step-0 tile into half 0 (its last reader was step NK-2)
    if (NEXTK == 0) stage32(nextTc, bbuf, wid, lane);
    if (NEXTK == 1) stageH(nextTc, bbuf, wid, lane);
    __syncthreads();
}

__launch_bounds__(512, 2)
__global__ void ens_mlp(const unsigned short* __restrict__ X,
                        const unsigned short* __restrict__ T1c, const unsigned short* __restrict__ T2c,
                        const unsigned short* __restrict__ T3c, const unsigned short* __restrict__ T4c,
                        const unsigned short* __restrict__ THc,
                        const float* __restrict__ b1, const float* __restrict__ b2,
                        const float* __restrict__ b3, const float* __restrict__ b4,
                        const float* __restrict__ BH,
                        const float* __restrict__ dmean, const float* __restrict__ dstd,
                        float* __restrict__ out) {
    __shared__ alignas(16) unsigned short hbuf[TM * HID];   // 64 KB activations
    __shared__ alignas(16) unsigned short bbuf[32768];      // 2 x 32 KB B double buffer
    const int bid = blockIdx.x;
    const int e = bid & 7;                      // ensemble -> XCD affinity
    const int tile = bid >> 3;
    const int row0 = tile * TM;
    const int tid = threadIdx.x, lane = tid & 63, wid = tid >> 6;

    const unsigned short* T1e = T1c + (size_t)e * 2  * 2048 * 8;
    const unsigned short* T2e = T2c + (size_t)e * 16 * 2048 * 8;
    const unsigned short* T3e = T3c + (size_t)e * 16 * 2048 * 8;
    const unsigned short* T4e = T4c + (size_t)e * 16 * 2048 * 8;
    const unsigned short* THe = THc + (size_t)e * 16 * 320 * 8;

    // stage X tile (64 rows x 64 bf16, swizzled) + L1 step-0 B tile
    {
        int r = tid >> 3, c = tid & 7;          // 16B chunk index
        int4 v = *(const int4*)(X + (size_t)(row0 + r) * DINP + c * 8);
        *(int4*)((char*)hbuf + r * 1024 + ((c ^ (r & 7)) << 4)) = v;
    }
    stage32(T1e, bbuf, wid, lane);
    __syncthreads();

    mlp_layer<2,  0>(T1e, T2e, b1 + e * HID, hbuf, bbuf, lane, wid);
    mlp_layer<16, 0>(T2e, T3e, b2 + e * HID, hbuf, bbuf, lane, wid);
    mlp_layer<16, 0>(T3e, T4e, b3 + e * HID, hbuf, bbuf, lane, wid);
    mlp_layer<16, 1>(T4e, THe, b4 + e * HID, hbuf, bbuf, lane, wid);

    // ---- heads: 20 tile-jobs (rt 0..3, ct 0..4) over 8 waves, staged B ----
    const int l15 = lane & 15, lk = (lane >> 4) * 8, kc = lane >> 4;
    const int j0 = wid, j1 = wid + 8, j2 = wid + 16;
    const bool has2 = (j2 < 20);
    const int rt0 = j0 / 5, ct0 = j0 % 5;
    const int rt1 = j1 / 5, ct1 = j1 % 5;
    const int rt2 = has2 ? j2 / 5 : 0, ct2 = has2 ? j2 % 5 : 0;
    const float* BHe = BH + e * NH;

    f32x4 h0, h1, h2;
    { float bv = BHe[ct0 * 16 + l15]; h0 = (f32x4){bv, bv, bv, bv}; }
    { float bv = BHe[ct1 * 16 + l15]; h1 = (f32x4){bv, bv, bv, bv}; }
    { float bv = BHe[ct2 * 16 + l15]; h2 = (f32x4){bv, bv, bv, bv}; }

    #pragma unroll
    for (int ks = 0; ks < 16; ++ks) {
        if (ks + 1 < 16)
            stageH(THe + (size_t)(ks + 1) * 320 * 8, bbuf + ((ks + 1) & 1) * 16384, wid, lane);
        const unsigned short* bb = bbuf + (ks & 1) * 16384;
        const int k = ks * 32 + lk;

        bf16x8 a0 = load_a(hbuf, rt0 * 16 + l15, k);
        bf16x8 w0 = *(const bf16x8*)(bb + (size_t)(kc * NH + ct0 * 16 + l15) * 8);
        h0 = __builtin_amdgcn_mfma_f32_16x16x32_bf16(a0, w0, h0, 0, 0, 0);
        bf16x8 a1 = load_a(hbuf, rt1 * 16 + l15, k);
        bf16x8 w1 = *(const bf16x8*)(bb + (size_t)(kc * NH + ct1 * 16 + l15) * 8);
        h1 = __builtin_amdgcn_mfma_f32_16x16x32_bf16(a1, w1, h1, 0, 0, 0);
        if (has2) {
            bf16x8 a2 = load_a(hbuf, rt2 * 16 + l15, k);
            bf16x8 w2 = *(const bf16x8*)(bb + (size_t)(kc * NH + ct2 * 16 + l15) * 8);
            h2 = __builtin_amdgcn_mfma_f32_16x16x32_bf16(a2, w2, h2, 0, 0, 0);
        }
        __syncthreads();
    }

    // ---- epilogue: clip/exp/denorm, write concatenated fp32 outputs ----
    const size_t STDS_OFF = (size_t)NE * BTOT * OBS;
    const size_t REW_OFF  = 2 * STDS_OFF;
    const size_t DONE_OFF = REW_OFF + (size_t)NE * BTOT;

    auto emit = [&](int rt, int ct, f32x4 v) {
        int col = ct * 16 + l15;
        #pragma unroll
        for (int j = 0; j < 4; ++j) {
            int row = row0 + rt * 16 + (lane >> 4) * 4 + j;
            size_t rb = (size_t)e * BTOT + row;
            float x = v[j];
            if (col < 32) {
                out[rb * 32 + col] = x * dstd[col] + dmean[col];
            } else if (col < 64) {
                int c = col - 32;
                float ls = fminf(fmaxf(x, -10.f), 0.5f);
                out[STDS_OFF + rb * 32 + c] = expf(ls) * dstd[c];
            } else if (col == 64) {
                out[REW_OFF + rb] = x;
            } else if (col == 65) {
                out[DONE_OFF + rb] = x;
            }
        }
    };
    emit(rt0, ct0, h0);
    emit(rt1, ct1, h1);
    if (has2) emit(rt2, ct2, h2);
}

// ---------------- launch ----------------

extern "C" void kernel_launch(void* const* d_in, const int* in_sizes, int n_in,
                              void* d_out, int out_size, void* d_ws, size_t ws_size,
                              hipStream_t stream) {
    const float* states  = (const float*)d_in[0];
    const float* actions = (const float*)d_in[1];
    const float* smean   = (const float*)d_in[2];
    const float* sstd    = (const float*)d_in[3];
    const float* amean   = (const float*)d_in[4];
    const float* astd    = (const float*)d_in[5];
    const float* dmean   = (const float*)d_in[6];
    const float* dstd    = (const float*)d_in[7];
    const float* W1 = (const float*)d_in[8];
    const float* b1 = (const float*)d_in[9];
    const float* W2 = (const float*)d_in[10];
    const float* b2 = (const float*)d_in[11];
    const float* W3 = (const float*)d_in[12];
    const float* b3 = (const float*)d_in[13];
    const float* W4 = (const float*)d_in[14];
    const float* b4 = (const float*)d_in[15];
    const float* Wm = (const float*)d_in[16];
    const float* bm = (const float*)d_in[17];
    const float* Wls = (const float*)d_in[18];
    const float* bls = (const float*)d_in[19];
    const float* Wr = (const float*)d_in[20];
    const float* br = (const float*)d_in[21];
    const float* Wd = (const float*)d_in[22];
    const float* bd = (const float*)d_in[23];

    char* ws = (char*)d_ws;
    unsigned short* X   = (unsigned short*)(ws);                // 4,194,304 B
    unsigned short* T1c = (unsigned short*)(ws + 4194304);      //   524,288 B
    unsigned short* T2c = (unsigned short*)(ws + 4718592);      // 4,194,304 B
    unsigned short* T3c = (unsigned short*)(ws + 8912896);
    unsigned short* T4c = (unsigned short*)(ws + 13107200);
    unsigned short* THc = (unsigned short*)(ws + 17301504);     //   655,360 B
    float*          BH  = (float*)(ws + 17956864);              //     2,560 B

    prep_x<<<(BTOT * 64) / 256, 256, 0, stream>>>(states, actions, smean, sstd, amean, astd, X);
    prep_w1<<<(NE * 2 * 4 * 512) / 256, 256, 0, stream>>>(W1, T1c);
    prep_wh<<<(24 * 32768) / 256, 256, 0, stream>>>(W2, W3, W4, T2c, T3c, T4c);
    prep_head<<<(NE * 16 * 4 * NH + 255) / 256, 256, 0, stream>>>(Wm, Wls, Wr, Wd, bm, bls, br, bd, THc, BH);

    ens_mlp<<<NE * (BTOT / TM), 512, 0, stream>>>(X, T1c, T2c, T3c, T4c, THc,
                                                  b1, b2, b3, b4, BH, dmean, dstd,
                                                  (float*)d_out);
}